// Round 23
// baseline (790.044 us; speedup 1.0000x reference)
//
#include <hip/hip_runtime.h>
#include <hip/hip_bf16.h>
#include <cstdint>
#include <cstddef>
#include <type_traits>

// ---------------- problem constants ----------------
constexpr int B_   = 2;
constexpr int L_   = 2048;
constexpr int F_   = 128;
constexpr int DM_  = 768;
constexpr int NL_  = 4;
constexpr int DS_  = 16;
constexpr int DC_  = 4;
constexpr int DI_  = 2 * DM_;          // 1536
constexpr int DR_  = (DM_ + 15) / 16;  // 48
constexpr int BL_  = B_ * L_;          // 4096 rows
constexpr int NXZ_ = 2 * DI_;          // 3072
constexpr int DBC_ = DR_ + 2 * DS_;    // 80
constexpr int NCH_ = 64;               // scan chunks
constexpr int TCH_ = L_ / NCH_;        // 32 timesteps per chunk
constexpr int LBLK = 64;               // conv l-strip

#define DEV_INLINE __device__ __forceinline__

typedef __attribute__((ext_vector_type(8))) short  bf16x8;
typedef __attribute__((ext_vector_type(4))) float  f32x4;

DEV_INLINE float sigmoidf_(float x) { return 1.f / (1.f + __expf(-x)); }
DEV_INLINE float siluf_(float x)    { return x * sigmoidf_(x); }
DEV_INLINE float softplusf_(float x){ return x > 20.f ? x : log1pf(expf(x)); }

DEV_INLINE void gload_lds16(const void* g, void* l) {
    __builtin_amdgcn_global_load_lds(
        (const __attribute__((address_space(1))) void*)g,
        (__attribute__((address_space(3))) void*)l, 16, 0, 0);
}

// bijective XCD swizzle (m204)
DEV_INLINE void swz_xy(int nx, int& bx, int& by) {
    const int nwg = nx * gridDim.y;
    const int wg  = blockIdx.y * nx + blockIdx.x;
    const int q = nwg >> 3, r = nwg & 7;
    const int xcd = wg & 7, lx = wg >> 3;
    const int s = (xcd < r ? xcd * (q + 1) : r * (q + 1) + (xcd - r) * q) + lx;
    bx = s % nx;
    by = s / nx;
}

// ---------------- bf16 MFMA GEMM, BK=64, swizzled LDS ----
// DBUF=true : 2-phase double-buffered (R10-verified).
// DBUF=false: single-buffered — 32 MFMA per barrier pair at BN=128 (R15-verified).
template<int BN, typename CT, bool BIAS, bool SOFTPLUS, bool ACCUM, bool NMASK,
         int SPLITK = 1, bool DBUF = true>
__global__ __launch_bounds__(256)
void gemm_mfma(const __hip_bfloat16* __restrict__ A,
               const __hip_bfloat16* __restrict__ Bt,
               CT* __restrict__ C, int ldc,
               const float* __restrict__ bias,
               int K, int Nreal)
{
    constexpr int NFR  = BN / 32;
    constexpr int NBUF = DBUF ? 2 : 1;
    __shared__ __hip_bfloat16 As[NBUF][128 * 64];
    __shared__ __hip_bfloat16 Bs[NBUF][BN * 64];

    const int tid  = threadIdx.x;
    const int lane = tid & 63;
    const int wv   = tid >> 6;
    const int wr   = wv >> 1;
    const int wc   = wv & 1;
    int bx, by;
    swz_xy(gridDim.x, bx, by);
    const int row0 = by * 128;
    const int col0 = bx * BN;

    const int trow = tid >> 3;
    const int slot_src = (tid & 7) ^ (trow & 7);
    const int scol = slot_src * 8;

    const int fr = lane & 15, fq = lane >> 4;

    const int Kslice = K / SPLITK;
    const int kbeg   = (SPLITK > 1) ? blockIdx.z * Kslice : 0;
    const int nt     = Kslice / 64;

    f32x4 acc[4][NFR] = {};

    auto stage = [&](int buf, int k0) {
        #pragma unroll
        for (int j = 0; j < 4; ++j)
            gload_lds16(A + (size_t)(row0 + j * 32 + trow) * K + k0 + scol,
                        (char*)&As[buf][0] + j * 4096 + tid * 16);
        #pragma unroll
        for (int j = 0; j < BN / 32; ++j)
            gload_lds16(Bt + (size_t)(col0 + j * 32 + trow) * K + k0 + scol,
                        (char*)&Bs[buf][0] + j * 4096 + tid * 16);
    };

    auto aoff = [&](int row, int kk) { return row * 64 + (((kk << 2) + fq) ^ (row & 7)) * 8; };

    auto compute = [&](int buf) {
        #pragma unroll
        for (int kk = 0; kk < 2; ++kk) {
            bf16x8 af[4], bfv[NFR];
            #pragma unroll
            for (int m = 0; m < 4; ++m)
                af[m] = *(const bf16x8*)&As[buf][aoff(wr * 64 + m * 16 + fr, kk)];
            #pragma unroll
            for (int n = 0; n < NFR; ++n)
                bfv[n] = *(const bf16x8*)&Bs[buf][aoff(wc * (BN / 2) + n * 16 + fr, kk)];
            #pragma unroll
            for (int m = 0; m < 4; ++m)
                #pragma unroll
                for (int n = 0; n < NFR; ++n)
                    acc[m][n] = __builtin_amdgcn_mfma_f32_16x16x32_bf16(
                        af[m], bfv[n], acc[m][n], 0, 0, 0);
        }
    };

    if constexpr (DBUF) {
        int cur = 0;
        stage(0, kbeg);
        __syncthreads();
        for (int t = 0; t < nt; ++t) {
            if (t + 1 < nt) stage(cur ^ 1, kbeg + (t + 1) * 64);
            compute(cur);
            __syncthreads();
            cur ^= 1;
        }
    } else {
        for (int t = 0; t < nt; ++t) {
            stage(0, kbeg + t * 64);
            __syncthreads();
            compute(0);
            __syncthreads();
        }
    }

    #pragma unroll
    for (int m = 0; m < 4; ++m) {
        #pragma unroll
        for (int n = 0; n < NFR; ++n) {
            const int col = col0 + wc * (BN / 2) + n * 16 + fr;
            if (NMASK && col >= Nreal) continue;
            #pragma unroll
            for (int r = 0; r < 4; ++r) {
                const int row = row0 + wr * 64 + m * 16 + fq * 4 + r;
                float v = acc[m][n][r];
                if constexpr (SPLITK > 1) {
                    atomicAdd((float*)&C[(size_t)row * ldc + col], v);
                } else {
                    if (BIAS)     v += bias[col];
                    if (SOFTPLUS) v = softplusf_(v);
                    if (ACCUM)    v += (float)C[(size_t)row * ldc + col];
                    if constexpr (std::is_same<CT, __hip_bfloat16>::value)
                        C[(size_t)row * ldc + col] = __float2bfloat16(v);
                    else
                        C[(size_t)row * ldc + col] = v;
                }
            }
        }
    }
}

// ---- f32 [K][N] -> bf16 [Npad][Kpad] transpose, layer-batched, K-padded ----
__global__ __launch_bounds__(256)
void transpose_f32_bf16(const float* __restrict__ in, __hip_bfloat16* __restrict__ out,
                        int K, int N, int Kpad, size_t in_stride, size_t out_stride)
{
    __shared__ float t[32][33];
    const float* inp = in + blockIdx.z * in_stride;
    __hip_bfloat16* outp = out + blockIdx.z * out_stride;
    const int n0 = blockIdx.x * 32, k0 = blockIdx.y * 32;
    const int tx = threadIdx.x, ty = threadIdx.y;
    #pragma unroll
    for (int r = 0; r < 4; ++r) {
        const int k = k0 + ty + r * 8;
        const int n = n0 + tx;
        t[ty + r * 8][tx] = (n < N && k < K) ? inp[(size_t)k * N + n] : 0.f;
    }
    __syncthreads();
    #pragma unroll
    for (int r = 0; r < 4; ++r) {
        const int n = n0 + ty + r * 8;
        const int k = k0 + tx;
        outp[(size_t)n * Kpad + k] = __float2bfloat16(t[tx][ty + r * 8]);
    }
}

__global__ __launch_bounds__(256)
void cvt_bf16(const float* __restrict__ in, __hip_bfloat16* __restrict__ out, int n)
{
    const int i = blockIdx.x * 256 + threadIdx.x;
    if (i < n) out[i] = __float2bfloat16(in[i]);
}

// ------- row LayerNorm (768 = 3*256); optionally zeroes zbuf as a side job --
template<typename OT>
__global__ __launch_bounds__(256)
void ln_rows(const float* __restrict__ x, const float* __restrict__ g,
             const float* __restrict__ bb, OT* __restrict__ o,
             float* __restrict__ zbuf, int zn)
{
    const int r = blockIdx.x;
    const float* xr = x + (size_t)r * DM_;
    const int tid = threadIdx.x;

    if (zbuf) {
        const int zi = r * 256 + tid;
        if (zi < zn) zbuf[zi] = 0.f;
    }

    float v[3];
    float sum = 0.f, sumsq = 0.f;
    #pragma unroll
    for (int j = 0; j < 3; ++j) {
        v[j] = xr[tid + j * 256];
        sum   += v[j];
        sumsq += v[j] * v[j];
    }
    #pragma unroll
    for (int off = 32; off > 0; off >>= 1) {
        sum   += __shfl_xor(sum, off);
        sumsq += __shfl_xor(sumsq, off);
    }
    __shared__ float ws[2][4];
    const int lane = tid & 63, wid = tid >> 6;
    if (lane == 0) { ws[0][wid] = sum; ws[1][wid] = sumsq; }
    __syncthreads();
    const float ts  = ws[0][0] + ws[0][1] + ws[0][2] + ws[0][3];
    const float tsq = ws[1][0] + ws[1][1] + ws[1][2] + ws[1][3];
    const float m   = ts / DM_;
    const float var = tsq / DM_ - m * m;
    const float rs  = rsqrtf(var + 1e-5f);
    OT* orow = o + (size_t)r * DM_;
    #pragma unroll
    for (int j = 0; j < 3; ++j) {
        const int c = tid + j * 256;
        orow[c] = OT((v[j] - m) * rs * g[c] + bb[c]);
    }
}

// ------- depthwise causal conv (DC=4) + SiLU, sliding-window, 1 load/out ----
__global__ __launch_bounds__(256)
void conv_silu(const __hip_bfloat16* __restrict__ xz, const float* __restrict__ cw,
               const float* __restrict__ cb, __hip_bfloat16* __restrict__ u)
{
    const int nd = DI_ / 256;
    const int db = blockIdx.x % nd;
    const int lb = (blockIdx.x / nd) % (L_ / LBLK);
    const int b  = blockIdx.x / (nd * (L_ / LBLK));
    const int d  = db * 256 + threadIdx.x;
    const int l0 = lb * LBLK;

    const float w0 = cw[d * DC_ + 0], w1 = cw[d * DC_ + 1];
    const float w2 = cw[d * DC_ + 2], w3 = cw[d * DC_ + 3];
    const float bias = cb[d];

    const size_t base = (size_t)(b * L_) * NXZ_ + d;
    auto ld = [&](int l) -> float {
        return (l >= 0) ? __bfloat162float(xz[base + (size_t)l * NXZ_]) : 0.f;
    };

    float xm3 = ld(l0 - 3), xm2 = ld(l0 - 2), xm1 = ld(l0 - 1);
    for (int l = l0; l < l0 + LBLK; ++l) {
        const float xl = ld(l);
        const float acc = fmaf(xm3, w0, fmaf(xm2, w1, fmaf(xm1, w2, fmaf(xl, w3, bias))));
        u[(size_t)(b * L_ + l) * DI_ + d] = __float2bfloat16(siluf_(acc));
        xm3 = xm2; xm2 = xm1; xm1 = xl;
    }
}

// ---------------- chunked selective scan ----------------
template<bool PROG>
DEV_INLINE void calc_pw(float dv, const float* Ar, float* pw)
{
    if (PROG) {
        pw[0] = __expf(dv * Ar[0]);
        #pragma unroll
        for (int n = 1; n < DS_; ++n) pw[n] = pw[(n - 1) >> 1] * pw[n >> 1];
    } else {
        #pragma unroll
        for (int n = 0; n < DS_; ++n) pw[n] = __expf(dv * Ar[n]);
    }
}

DEV_INLINE bool prog_check(const float* Ar)
{
    bool prog = true;
    #pragma unroll
    for (int n = 1; n < DS_; ++n)
        prog = prog && (fabsf(Ar[n] - Ar[0] * (n + 1)) <= 1e-4f * fabsf(Ar[n]) + 1e-30f);
    return prog;
}

// pass A + fused dt.  R23: (b,c) derived from blockIdx ALONE (6 blocks per
// (b,c) since DI_ = 6*256), so the dbc row pointer is compiler-provably
// WAVE-UNIFORM -> dbc reads become s_load into SGPRs (scalar cache), removing
// the ~18K ds_read/CU LDS-issue bottleneck that pinned passA at 55 us
// (R18/R19/R20 loop-shape changes were all null: LDS issue, not VALU/VGPR).
// No LDS staging at all.  Values and FP order bit-identical to R18.
__global__ __launch_bounds__(256, 3)
void scan_passA(const float* __restrict__ dbc, const __hip_bfloat16* __restrict__ u,
                const float* __restrict__ A_log, const float* __restrict__ dt_w,
                const float* __restrict__ dt_b,
                float* __restrict__ cs, float* __restrict__ csum,
                __hip_bfloat16* __restrict__ delta)
{
    const int tid  = threadIdx.x;
    const int blk6 = blockIdx.x / 6;               // (b,c) index: uniform
    const int d    = (blockIdx.x % 6) * 256 + tid; // same mapping as t0 % DI_
    const int c    = blk6 % NCH_;
    const int b    = blk6 / NCH_;
    const int rowbase = b * L_ + c * TCH_;         // blockIdx-only -> uniform

    float Ar[DS_];
    #pragma unroll
    for (int n = 0; n < DS_; ++n) Ar[n] = -__expf(A_log[d * DS_ + n]);
    const bool prog = prog_check(Ar);

    float dtw_r[DR_];
    #pragma unroll
    for (int k = 0; k < DR_; ++k) dtw_r[k] = dt_w[(size_t)k * DI_ + d];
    const float bv = dt_b[d];

    float s[DS_] = {};
    float sumd = 0.f;

    auto run = [&](auto PROGC) {
        constexpr bool PROG = decltype(PROGC)::value;
        for (int t = 0; t < TCH_; ++t) {
            const int row = rowbase + t;
            const float* drow = dbc + (size_t)row * DBC_;   // uniform -> s_load
            // fused dt: delta_t = softplus(dbc_row . dt_w + b), bf16-rounded
            float a = bv;
            #pragma unroll
            for (int k = 0; k < DR_; ++k) a = fmaf(drow[k], dtw_r[k], a);
            const __hip_bfloat16 db16 = __float2bfloat16(softplusf_(a));
            delta[(size_t)row * DI_ + d] = db16;
            const float dv = __bfloat162float(db16);

            const float uv = __bfloat162float(u[(size_t)row * DI_ + d]);
            const float du = dv * uv;
            sumd += dv;
            float pw[DS_];
            calc_pw<PROG>(dv, Ar, pw);
            #pragma unroll
            for (int n = 0; n < DS_; ++n)
                s[n] = fmaf(s[n], pw[n], du * drow[DR_ + n]);
        }
    };
    if (prog) run(std::true_type{}); else run(std::false_type{});

    const size_t cbase = ((size_t)(b * NCH_ + c) * DS_) * DI_ + d;
    #pragma unroll
    for (int n = 0; n < DS_; ++n) cs[cbase + (size_t)n * DI_] = s[n];
    csum[(size_t)(b * NCH_ + c) * DI_ + d] = sumd;
}

__global__ __launch_bounds__(256)
void scan_passB(float* __restrict__ cs, const float* __restrict__ csum,
                const float* __restrict__ A_log)
{
    const int t0 = blockIdx.x * 256 + threadIdx.x;
    const int d = t0 % DI_;
    const int n = (t0 / DI_) % DS_;
    const int b = t0 / (DI_ * DS_);
    const float An = -__expf(A_log[d * DS_ + n]);

    float carry = 0.f;
    for (int c = 0; c < NCH_; ++c) {
        const size_t idx = ((size_t)(b * NCH_ + c) * DS_ + n) * DI_ + d;
        const float loc = cs[idx];
        cs[idx] = carry;
        carry = fmaf(carry, __expf(An * csum[(size_t)(b * NCH_ + c) * DI_ + d]), loc);
    }
}

// pass C: same uniform-(b,c) decomposition so dbc B/C reads scalarize too.
__global__ __launch_bounds__(256, 3)
void scan_passC(const __hip_bfloat16* __restrict__ delta, const __hip_bfloat16* __restrict__ u,
                const float* __restrict__ dbc, const float* __restrict__ A_log,
                const float* __restrict__ cs, const float* __restrict__ Dvp,
                const __hip_bfloat16* __restrict__ xz, __hip_bfloat16* __restrict__ y)
{
    const int tid  = threadIdx.x;
    const int blk6 = blockIdx.x / 6;
    const int d    = (blockIdx.x % 6) * 256 + tid;
    const int c    = blk6 % NCH_;
    const int b    = blk6 / NCH_;
    const int rowbase = b * L_ + c * TCH_;

    float Ar[DS_];
    #pragma unroll
    for (int n = 0; n < DS_; ++n) Ar[n] = -__expf(A_log[d * DS_ + n]);
    const bool prog = prog_check(Ar);

    float s[DS_];
    const size_t cbase = ((size_t)(b * NCH_ + c) * DS_) * DI_ + d;
    #pragma unroll
    for (int n = 0; n < DS_; ++n) s[n] = cs[cbase + (size_t)n * DI_];

    const float Dvd = Dvp[d];

    auto run = [&](auto PROGC) {
        constexpr bool PROG = decltype(PROGC)::value;
        for (int t = 0; t < TCH_; ++t) {
            const int row = rowbase + t;
            const float* drow = dbc + (size_t)row * DBC_ + DR_;  // uniform -> s_load
            const float dv = __bfloat162float(delta[(size_t)row * DI_ + d]);
            const float uv = __bfloat162float(u[(size_t)row * DI_ + d]);
            const float du = dv * uv;
            float pw[DS_];
            calc_pw<PROG>(dv, Ar, pw);
            float yv = 0.f;
            #pragma unroll
            for (int n = 0; n < DS_; ++n) {
                s[n] = fmaf(s[n], pw[n], du * drow[n]);
                yv = fmaf(s[n], drow[DS_ + n], yv);
            }
            yv = fmaf(uv, Dvd, yv);
            const float zv = __bfloat162float(xz[(size_t)row * NXZ_ + DI_ + d]);
            yv *= siluf_(zv);
            y[(size_t)row * DI_ + d] = __float2bfloat16(yv);
        }
    };
    if (prog) run(std::true_type{}); else run(std::false_type{});
}

// ---------------- host launch ----------------
extern "C" void kernel_launch(void* const* d_in, const int* in_sizes, int n_in,
                              void* d_out, int out_size, void* d_ws, size_t ws_size,
                              hipStream_t stream)
{
    const float* x      = (const float*)d_in[0];
    const float* Wi     = (const float*)d_in[1];
    const float* bi     = (const float*)d_in[2];
    const float* ln_g   = (const float*)d_in[3];
    const float* ln_b   = (const float*)d_in[4];
    const float* in_w   = (const float*)d_in[5];
    const float* conv_w = (const float*)d_in[6];
    const float* conv_b = (const float*)d_in[7];
    const float* xproj  = (const float*)d_in[8];
    const float* dt_w   = (const float*)d_in[9];
    const float* dt_b   = (const float*)d_in[10];
    const float* A_log  = (const float*)d_in[11];
    const float* Dvp    = (const float*)d_in[12];
    const float* out_w  = (const float*)d_in[13];
    const float* fn_g   = (const float*)d_in[14];
    const float* fn_b   = (const float*)d_in[15];
    float* out = (float*)d_out;

    float* ws = (float*)d_ws;
    size_t off = 0;
    auto alloc = [&](size_t nfloats) { float* p = ws + off; off += nfloats; return p; };

    float* h     = alloc((size_t)BL_ * DM_);
    float* dbc   = alloc((size_t)BL_ * DBC_);
    float* cs    = alloc((size_t)B_ * NCH_ * DS_ * DI_);
    float* csum  = alloc((size_t)B_ * NCH_ * DI_);
    __hip_bfloat16* delta = (__hip_bfloat16*)alloc((size_t)BL_ * DI_ / 2);
    __hip_bfloat16* xz_bf = (__hip_bfloat16*)alloc((size_t)BL_ * NXZ_ / 2);
    __hip_bfloat16* hn_bf = (__hip_bfloat16*)alloc((size_t)BL_ * DM_ / 2);
    __hip_bfloat16* u_bf  = (__hip_bfloat16*)alloc((size_t)BL_ * DI_ / 2);
    __hip_bfloat16* y_bf  = (__hip_bfloat16*)alloc((size_t)BL_ * DI_ / 2);
    __hip_bfloat16* WiT   = (__hip_bfloat16*)alloc((size_t)DM_ * F_ / 2);
    __hip_bfloat16* x_bf  = (__hip_bfloat16*)alloc((size_t)BL_ * F_ / 2);
    __hip_bfloat16* inT   = (__hip_bfloat16*)alloc((size_t)NL_ * NXZ_ * DM_ / 2);
    __hip_bfloat16* outT  = (__hip_bfloat16*)alloc((size_t)NL_ * DM_ * DI_ / 2);
    __hip_bfloat16* xprT  = (__hip_bfloat16*)alloc((size_t)NL_ * 128 * DI_ / 2);

    const dim3 blk(256);
    const dim3 tblk(32, 8);

    // ---- all weight conversions up front (layer-batched via gridDim.z) ----
    cvt_bf16<<<(BL_ * F_ + 255) / 256, blk, 0, stream>>>(x, x_bf, BL_ * F_);
    transpose_f32_bf16<<<dim3(DM_ / 32, F_ / 32, 1), tblk, 0, stream>>>(
        Wi, WiT, F_, DM_, F_, 0, 0);
    transpose_f32_bf16<<<dim3(NXZ_ / 32, DM_ / 32, NL_), tblk, 0, stream>>>(
        in_w, inT, DM_, NXZ_, DM_, (size_t)DM_ * NXZ_, (size_t)NXZ_ * DM_);
    transpose_f32_bf16<<<dim3(DM_ / 32, DI_ / 32, NL_), tblk, 0, stream>>>(
        out_w, outT, DI_, DM_, DI_, (size_t)DI_ * DM_, (size_t)DM_ * DI_);
    transpose_f32_bf16<<<dim3(128 / 32, DI_ / 32, NL_), tblk, 0, stream>>>(
        xproj, xprT, DI_, DBC_, DI_, (size_t)DI_ * DBC_, (size_t)128 * DI_);

    // input projection: h = x @ Wi + bi  (BN=64, dbuf)
    gemm_mfma<64, float, true, false, false, false>
        <<<dim3(DM_ / 64, BL_ / 128), blk, 0, stream>>>(
        x_bf, WiT, h, DM_, bi, F_, DM_);

    for (int i = 0; i < NL_; ++i) {
        // ln + side-job: zero dbc for the split-K xproj below
        ln_rows<__hip_bfloat16><<<BL_, blk, 0, stream>>>(
            h, ln_g + i * DM_, ln_b + i * DM_, hn_bf, dbc, BL_ * DBC_);

        // xz: BN=128, single-buffered (32 MFMA per barrier pair) -> 768 blocks
        gemm_mfma<128, __hip_bfloat16, false, false, false, false, 1, false>
            <<<dim3(NXZ_ / 128, BL_ / 128), blk, 0, stream>>>(
            hn_bf, inT + (size_t)i * NXZ_ * DM_, xz_bf, NXZ_, nullptr, DM_, NXZ_);

        conv_silu<<<(DI_ / 256) * (L_ / LBLK) * B_, blk, 0, stream>>>(
            xz_bf, conv_w + (size_t)i * DI_ * DC_, conv_b + (size_t)i * DI_, u_bf);

        gemm_mfma<64, float, false, false, false, true, 8>
            <<<dim3(2, BL_ / 128, 8), blk, 0, stream>>>(
            u_bf, xprT + (size_t)i * 128 * DI_, dbc, DBC_, nullptr, DI_, DBC_);

        // pass A with fused dt (uniform dbc reads -> s_load, no LDS)
        scan_passA<<<(B_ * NCH_ * DI_) / 256, blk, 0, stream>>>(
            dbc, u_bf, A_log + (size_t)i * DI_ * DS_,
            dt_w + (size_t)i * DR_ * DI_, dt_b + (size_t)i * DI_,
            cs, csum, delta);
        scan_passB<<<(B_ * DS_ * DI_) / 256, blk, 0, stream>>>(
            cs, csum, A_log + (size_t)i * DI_ * DS_);
        scan_passC<<<(B_ * NCH_ * DI_) / 256, blk, 0, stream>>>(
            delta, u_bf, dbc, A_log + (size_t)i * DI_ * DS_, cs, Dvp + (size_t)i * DI_,
            xz_bf, y_bf);

        // out-proj: BN=128 single-buffered, split-K x2 -> 384 blocks
        gemm_mfma<128, float, false, false, false, false, 2, false>
            <<<dim3(DM_ / 128, BL_ / 128, 2), blk, 0, stream>>>(
            y_bf, outT + (size_t)i * DM_ * DI_, h, DM_, nullptr, DI_, DM_);
    }

    ln_rows<float><<<BL_, blk, 0, stream>>>(h, fn_g, fn_b, out, nullptr, 0);
}

// Round 24
// 766.853 us; speedup vs baseline: 1.0302x; 1.0302x over previous
//
#include <hip/hip_runtime.h>
#include <hip/hip_bf16.h>
#include <cstdint>
#include <cstddef>
#include <type_traits>

// ---------------- problem constants ----------------
constexpr int B_   = 2;
constexpr int L_   = 2048;
constexpr int F_   = 128;
constexpr int DM_  = 768;
constexpr int NL_  = 4;
constexpr int DS_  = 16;
constexpr int DC_  = 4;
constexpr int DI_  = 2 * DM_;          // 1536
constexpr int DR_  = (DM_ + 15) / 16;  // 48
constexpr int BL_  = B_ * L_;          // 4096 rows
constexpr int NXZ_ = 2 * DI_;          // 3072
constexpr int DBC_ = DR_ + 2 * DS_;    // 80
constexpr int NCH_ = 64;               // scan chunks
constexpr int TCH_ = L_ / NCH_;        // 32 timesteps per chunk
constexpr int LBLK = 64;               // conv l-strip

#define DEV_INLINE __device__ __forceinline__

typedef __attribute__((ext_vector_type(8))) short  bf16x8;
typedef __attribute__((ext_vector_type(4))) float  f32x4;

DEV_INLINE float sigmoidf_(float x) { return 1.f / (1.f + __expf(-x)); }
DEV_INLINE float siluf_(float x)    { return x * sigmoidf_(x); }
DEV_INLINE float softplusf_(float x){ return x > 20.f ? x : log1pf(expf(x)); }

DEV_INLINE void gload_lds16(const void* g, void* l) {
    __builtin_amdgcn_global_load_lds(
        (const __attribute__((address_space(1))) void*)g,
        (__attribute__((address_space(3))) void*)l, 16, 0, 0);
}

// bijective XCD swizzle (m204)
DEV_INLINE void swz_xy(int nx, int& bx, int& by) {
    const int nwg = nx * gridDim.y;
    const int wg  = blockIdx.y * nx + blockIdx.x;
    const int q = nwg >> 3, r = nwg & 7;
    const int xcd = wg & 7, lx = wg >> 3;
    const int s = (xcd < r ? xcd * (q + 1) : r * (q + 1) + (xcd - r) * q) + lx;
    bx = s % nx;
    by = s / nx;
}

// ---------------- bf16 MFMA GEMM, BK=64, swizzled LDS ----
// DBUF=true : 2-phase double-buffered (R10-verified).
// DBUF=false: single-buffered — 32 MFMA per barrier pair at BN=128 (R15-verified).
template<int BN, typename CT, bool BIAS, bool SOFTPLUS, bool ACCUM, bool NMASK,
         int SPLITK = 1, bool DBUF = true>
__global__ __launch_bounds__(256)
void gemm_mfma(const __hip_bfloat16* __restrict__ A,
               const __hip_bfloat16* __restrict__ Bt,
               CT* __restrict__ C, int ldc,
               const float* __restrict__ bias,
               int K, int Nreal)
{
    constexpr int NFR  = BN / 32;
    constexpr int NBUF = DBUF ? 2 : 1;
    __shared__ __hip_bfloat16 As[NBUF][128 * 64];
    __shared__ __hip_bfloat16 Bs[NBUF][BN * 64];

    const int tid  = threadIdx.x;
    const int lane = tid & 63;
    const int wv   = tid >> 6;
    const int wr   = wv >> 1;
    const int wc   = wv & 1;
    int bx, by;
    swz_xy(gridDim.x, bx, by);
    const int row0 = by * 128;
    const int col0 = bx * BN;

    const int trow = tid >> 3;
    const int slot_src = (tid & 7) ^ (trow & 7);
    const int scol = slot_src * 8;

    const int fr = lane & 15, fq = lane >> 4;

    const int Kslice = K / SPLITK;
    const int kbeg   = (SPLITK > 1) ? blockIdx.z * Kslice : 0;
    const int nt     = Kslice / 64;

    f32x4 acc[4][NFR] = {};

    auto stage = [&](int buf, int k0) {
        #pragma unroll
        for (int j = 0; j < 4; ++j)
            gload_lds16(A + (size_t)(row0 + j * 32 + trow) * K + k0 + scol,
                        (char*)&As[buf][0] + j * 4096 + tid * 16);
        #pragma unroll
        for (int j = 0; j < BN / 32; ++j)
            gload_lds16(Bt + (size_t)(col0 + j * 32 + trow) * K + k0 + scol,
                        (char*)&Bs[buf][0] + j * 4096 + tid * 16);
    };

    auto aoff = [&](int row, int kk) { return row * 64 + (((kk << 2) + fq) ^ (row & 7)) * 8; };

    auto compute = [&](int buf) {
        #pragma unroll
        for (int kk = 0; kk < 2; ++kk) {
            bf16x8 af[4], bfv[NFR];
            #pragma unroll
            for (int m = 0; m < 4; ++m)
                af[m] = *(const bf16x8*)&As[buf][aoff(wr * 64 + m * 16 + fr, kk)];
            #pragma unroll
            for (int n = 0; n < NFR; ++n)
                bfv[n] = *(const bf16x8*)&Bs[buf][aoff(wc * (BN / 2) + n * 16 + fr, kk)];
            #pragma unroll
            for (int m = 0; m < 4; ++m)
                #pragma unroll
                for (int n = 0; n < NFR; ++n)
                    acc[m][n] = __builtin_amdgcn_mfma_f32_16x16x32_bf16(
                        af[m], bfv[n], acc[m][n], 0, 0, 0);
        }
    };

    if constexpr (DBUF) {
        int cur = 0;
        stage(0, kbeg);
        __syncthreads();
        for (int t = 0; t < nt; ++t) {
            if (t + 1 < nt) stage(cur ^ 1, kbeg + (t + 1) * 64);
            compute(cur);
            __syncthreads();
            cur ^= 1;
        }
    } else {
        for (int t = 0; t < nt; ++t) {
            stage(0, kbeg + t * 64);
            __syncthreads();
            compute(0);
            __syncthreads();
        }
    }

    #pragma unroll
    for (int m = 0; m < 4; ++m) {
        #pragma unroll
        for (int n = 0; n < NFR; ++n) {
            const int col = col0 + wc * (BN / 2) + n * 16 + fr;
            if (NMASK && col >= Nreal) continue;
            #pragma unroll
            for (int r = 0; r < 4; ++r) {
                const int row = row0 + wr * 64 + m * 16 + fq * 4 + r;
                float v = acc[m][n][r];
                if constexpr (SPLITK > 1) {
                    atomicAdd((float*)&C[(size_t)row * ldc + col], v);
                } else {
                    if (BIAS)     v += bias[col];
                    if (SOFTPLUS) v = softplusf_(v);
                    if (ACCUM)    v += (float)C[(size_t)row * ldc + col];
                    if constexpr (std::is_same<CT, __hip_bfloat16>::value)
                        C[(size_t)row * ldc + col] = __float2bfloat16(v);
                    else
                        C[(size_t)row * ldc + col] = v;
                }
            }
        }
    }
}

// ---- f32 [K][N] -> bf16 [Npad][Kpad] transpose, layer-batched, K-padded ----
__global__ __launch_bounds__(256)
void transpose_f32_bf16(const float* __restrict__ in, __hip_bfloat16* __restrict__ out,
                        int K, int N, int Kpad, size_t in_stride, size_t out_stride)
{
    __shared__ float t[32][33];
    const float* inp = in + blockIdx.z * in_stride;
    __hip_bfloat16* outp = out + blockIdx.z * out_stride;
    const int n0 = blockIdx.x * 32, k0 = blockIdx.y * 32;
    const int tx = threadIdx.x, ty = threadIdx.y;
    #pragma unroll
    for (int r = 0; r < 4; ++r) {
        const int k = k0 + ty + r * 8;
        const int n = n0 + tx;
        t[ty + r * 8][tx] = (n < N && k < K) ? inp[(size_t)k * N + n] : 0.f;
    }
    __syncthreads();
    #pragma unroll
    for (int r = 0; r < 4; ++r) {
        const int n = n0 + ty + r * 8;
        const int k = k0 + tx;
        outp[(size_t)n * Kpad + k] = __float2bfloat16(t[tx][ty + r * 8]);
    }
}

__global__ __launch_bounds__(256)
void cvt_bf16(const float* __restrict__ in, __hip_bfloat16* __restrict__ out, int n)
{
    const int i = blockIdx.x * 256 + threadIdx.x;
    if (i < n) out[i] = __float2bfloat16(in[i]);
}

// ------- row LayerNorm (768 = 3*256); optionally zeroes zbuf as a side job --
template<typename OT>
__global__ __launch_bounds__(256)
void ln_rows(const float* __restrict__ x, const float* __restrict__ g,
             const float* __restrict__ bb, OT* __restrict__ o,
             float* __restrict__ zbuf, int zn)
{
    const int r = blockIdx.x;
    const float* xr = x + (size_t)r * DM_;
    const int tid = threadIdx.x;

    if (zbuf) {
        const int zi = r * 256 + tid;
        if (zi < zn) zbuf[zi] = 0.f;
    }

    float v[3];
    float sum = 0.f, sumsq = 0.f;
    #pragma unroll
    for (int j = 0; j < 3; ++j) {
        v[j] = xr[tid + j * 256];
        sum   += v[j];
        sumsq += v[j] * v[j];
    }
    #pragma unroll
    for (int off = 32; off > 0; off >>= 1) {
        sum   += __shfl_xor(sum, off);
        sumsq += __shfl_xor(sumsq, off);
    }
    __shared__ float ws[2][4];
    const int lane = tid & 63, wid = tid >> 6;
    if (lane == 0) { ws[0][wid] = sum; ws[1][wid] = sumsq; }
    __syncthreads();
    const float ts  = ws[0][0] + ws[0][1] + ws[0][2] + ws[0][3];
    const float tsq = ws[1][0] + ws[1][1] + ws[1][2] + ws[1][3];
    const float m   = ts / DM_;
    const float var = tsq / DM_ - m * m;
    const float rs  = rsqrtf(var + 1e-5f);
    OT* orow = o + (size_t)r * DM_;
    #pragma unroll
    for (int j = 0; j < 3; ++j) {
        const int c = tid + j * 256;
        orow[c] = OT((v[j] - m) * rs * g[c] + bb[c]);
    }
}

// ------- depthwise causal conv (DC=4) + SiLU, sliding-window, 1 load/out ----
__global__ __launch_bounds__(256)
void conv_silu(const __hip_bfloat16* __restrict__ xz, const float* __restrict__ cw,
               const float* __restrict__ cb, __hip_bfloat16* __restrict__ u)
{
    const int nd = DI_ / 256;
    const int db = blockIdx.x % nd;
    const int lb = (blockIdx.x / nd) % (L_ / LBLK);
    const int b  = blockIdx.x / (nd * (L_ / LBLK));
    const int d  = db * 256 + threadIdx.x;
    const int l0 = lb * LBLK;

    const float w0 = cw[d * DC_ + 0], w1 = cw[d * DC_ + 1];
    const float w2 = cw[d * DC_ + 2], w3 = cw[d * DC_ + 3];
    const float bias = cb[d];

    const size_t base = (size_t)(b * L_) * NXZ_ + d;
    auto ld = [&](int l) -> float {
        return (l >= 0) ? __bfloat162float(xz[base + (size_t)l * NXZ_]) : 0.f;
    };

    float xm3 = ld(l0 - 3), xm2 = ld(l0 - 2), xm1 = ld(l0 - 1);
    for (int l = l0; l < l0 + LBLK; ++l) {
        const float xl = ld(l);
        const float acc = fmaf(xm3, w0, fmaf(xm2, w1, fmaf(xm1, w2, fmaf(xl, w3, bias))));
        u[(size_t)(b * L_ + l) * DI_ + d] = __float2bfloat16(siluf_(acc));
        xm3 = xm2; xm2 = xm1; xm1 = xl;
    }
}

// ---------------- chunked selective scan ----------------
template<bool PROG>
DEV_INLINE void calc_pw(float dv, const float* Ar, float* pw)
{
    if (PROG) {
        pw[0] = __expf(dv * Ar[0]);
        #pragma unroll
        for (int n = 1; n < DS_; ++n) pw[n] = pw[(n - 1) >> 1] * pw[n >> 1];
    } else {
        #pragma unroll
        for (int n = 0; n < DS_; ++n) pw[n] = __expf(dv * Ar[n]);
    }
}

DEV_INLINE bool prog_check(const float* Ar)
{
    bool prog = true;
    #pragma unroll
    for (int n = 1; n < DS_; ++n)
        prog = prog && (fabsf(Ar[n] - Ar[0] * (n + 1)) <= 1e-4f * fabsf(Ar[n]) + 1e-30f);
    return prog;
}

// pass A + fused dt (R18/R21-verified best: 767 us total).  delta computed
// in-kernel (f32 FMA over LDS-staged dbc, rounded to bf16, written for passC,
// and the SAME rounded value used here).  Normal launch, no grid sync.
// NOTE: four reshaping attempts (k-outer, 4-acc split, launch_bounds(256,3),
// uniform-scalarization) all landed 55-60 us — this shape is the plateau.
__global__ __launch_bounds__(256)
void scan_passA(const float* __restrict__ dbc, const __hip_bfloat16* __restrict__ u,
                const float* __restrict__ A_log, const float* __restrict__ dt_w,
                const float* __restrict__ dt_b,
                float* __restrict__ cs, float* __restrict__ csum,
                __hip_bfloat16* __restrict__ delta)
{
    __shared__ float dbcS[TCH_][DBC_];   // 32 x 80 f32 = 10 KB
    const int t0 = blockIdx.x * 256 + threadIdx.x;
    const int d = t0 % DI_;
    const int c = (t0 / DI_) % NCH_;
    const int b = t0 / (DI_ * NCH_);
    const int rowbase = b * L_ + c * TCH_;

    for (int i = threadIdx.x; i < TCH_ * DBC_; i += 256) {
        dbcS[i / DBC_][i % DBC_] = dbc[(size_t)(rowbase + i / DBC_) * DBC_ + i % DBC_];
    }

    float Ar[DS_];
    #pragma unroll
    for (int n = 0; n < DS_; ++n) Ar[n] = -__expf(A_log[d * DS_ + n]);
    const bool prog = prog_check(Ar);

    float dtw_r[DR_];
    #pragma unroll
    for (int k = 0; k < DR_; ++k) dtw_r[k] = dt_w[(size_t)k * DI_ + d];
    const float bv = dt_b[d];

    __syncthreads();

    float s[DS_] = {};
    float sumd = 0.f;

    auto run = [&](auto PROGC) {
        constexpr bool PROG = decltype(PROGC)::value;
        for (int t = 0; t < TCH_; ++t) {
            const int row = rowbase + t;
            // fused dt: delta_t = softplus(dbc_row . dt_w + b), bf16-rounded
            float a = bv;
            #pragma unroll
            for (int k = 0; k < DR_; ++k) a = fmaf(dbcS[t][k], dtw_r[k], a);
            const __hip_bfloat16 db16 = __float2bfloat16(softplusf_(a));
            delta[(size_t)row * DI_ + d] = db16;
            const float dv = __bfloat162float(db16);

            const float uv = __bfloat162float(u[(size_t)row * DI_ + d]);
            const float du = dv * uv;
            sumd += dv;
            float pw[DS_];
            calc_pw<PROG>(dv, Ar, pw);
            #pragma unroll
            for (int n = 0; n < DS_; ++n)
                s[n] = fmaf(s[n], pw[n], du * dbcS[t][DR_ + n]);
        }
    };
    if (prog) run(std::true_type{}); else run(std::false_type{});

    const size_t cbase = ((size_t)(b * NCH_ + c) * DS_) * DI_ + d;
    #pragma unroll
    for (int n = 0; n < DS_; ++n) cs[cbase + (size_t)n * DI_] = s[n];
    csum[(size_t)(b * NCH_ + c) * DI_ + d] = sumd;
}

__global__ __launch_bounds__(256)
void scan_passB(float* __restrict__ cs, const float* __restrict__ csum,
                const float* __restrict__ A_log)
{
    const int t0 = blockIdx.x * 256 + threadIdx.x;
    const int d = t0 % DI_;
    const int n = (t0 / DI_) % DS_;
    const int b = t0 / (DI_ * DS_);
    const float An = -__expf(A_log[d * DS_ + n]);

    float carry = 0.f;
    for (int c = 0; c < NCH_; ++c) {
        const size_t idx = ((size_t)(b * NCH_ + c) * DS_ + n) * DI_ + d;
        const float loc = cs[idx];
        cs[idx] = carry;
        carry = fmaf(carry, __expf(An * csum[(size_t)(b * NCH_ + c) * DI_ + d]), loc);
    }
}

__global__ __launch_bounds__(256)
void scan_passC(const __hip_bfloat16* __restrict__ delta, const __hip_bfloat16* __restrict__ u,
                const float* __restrict__ dbc, const float* __restrict__ A_log,
                const float* __restrict__ cs, const float* __restrict__ Dvp,
                const __hip_bfloat16* __restrict__ xz, __hip_bfloat16* __restrict__ y)
{
    __shared__ float sBC[TCH_][2 * DS_];
    const int t0 = blockIdx.x * 256 + threadIdx.x;
    const int d = t0 % DI_;
    const int c = (t0 / DI_) % NCH_;
    const int b = t0 / (DI_ * NCH_);
    const int rowbase = b * L_ + c * TCH_;

    for (int i = threadIdx.x; i < TCH_ * 2 * DS_; i += 256) {
        const int t = i >> 5, j = i & 31;
        sBC[t][j] = dbc[(size_t)(rowbase + t) * DBC_ + DR_ + j];
    }

    float Ar[DS_];
    #pragma unroll
    for (int n = 0; n < DS_; ++n) Ar[n] = -__expf(A_log[d * DS_ + n]);
    const bool prog = prog_check(Ar);

    __syncthreads();

    float s[DS_];
    const size_t cbase = ((size_t)(b * NCH_ + c) * DS_) * DI_ + d;
    #pragma unroll
    for (int n = 0; n < DS_; ++n) s[n] = cs[cbase + (size_t)n * DI_];

    const float Dvd = Dvp[d];

    auto run = [&](auto PROGC) {
        constexpr bool PROG = decltype(PROGC)::value;
        for (int t = 0; t < TCH_; ++t) {
            const int row = rowbase + t;
            const float dv = __bfloat162float(delta[(size_t)row * DI_ + d]);
            const float uv = __bfloat162float(u[(size_t)row * DI_ + d]);
            const float du = dv * uv;
            float pw[DS_];
            calc_pw<PROG>(dv, Ar, pw);
            float yv = 0.f;
            #pragma unroll
            for (int n = 0; n < DS_; ++n) {
                s[n] = fmaf(s[n], pw[n], du * sBC[t][n]);
                yv = fmaf(s[n], sBC[t][DS_ + n], yv);
            }
            yv = fmaf(uv, Dvd, yv);
            const float zv = __bfloat162float(xz[(size_t)row * NXZ_ + DI_ + d]);
            yv *= siluf_(zv);
            y[(size_t)row * DI_ + d] = __float2bfloat16(yv);
        }
    };
    if (prog) run(std::true_type{}); else run(std::false_type{});
}

// ---------------- host launch ----------------
extern "C" void kernel_launch(void* const* d_in, const int* in_sizes, int n_in,
                              void* d_out, int out_size, void* d_ws, size_t ws_size,
                              hipStream_t stream)
{
    const float* x      = (const float*)d_in[0];
    const float* Wi     = (const float*)d_in[1];
    const float* bi     = (const float*)d_in[2];
    const float* ln_g   = (const float*)d_in[3];
    const float* ln_b   = (const float*)d_in[4];
    const float* in_w   = (const float*)d_in[5];
    const float* conv_w = (const float*)d_in[6];
    const float* conv_b = (const float*)d_in[7];
    const float* xproj  = (const float*)d_in[8];
    const float* dt_w   = (const float*)d_in[9];
    const float* dt_b   = (const float*)d_in[10];
    const float* A_log  = (const float*)d_in[11];
    const float* Dvp    = (const float*)d_in[12];
    const float* out_w  = (const float*)d_in[13];
    const float* fn_g   = (const float*)d_in[14];
    const float* fn_b   = (const float*)d_in[15];
    float* out = (float*)d_out;

    float* ws = (float*)d_ws;
    size_t off = 0;
    auto alloc = [&](size_t nfloats) { float* p = ws + off; off += nfloats; return p; };

    float* h     = alloc((size_t)BL_ * DM_);
    float* dbc   = alloc((size_t)BL_ * DBC_);
    float* cs    = alloc((size_t)B_ * NCH_ * DS_ * DI_);
    float* csum  = alloc((size_t)B_ * NCH_ * DI_);
    __hip_bfloat16* delta = (__hip_bfloat16*)alloc((size_t)BL_ * DI_ / 2);
    __hip_bfloat16* xz_bf = (__hip_bfloat16*)alloc((size_t)BL_ * NXZ_ / 2);
    __hip_bfloat16* hn_bf = (__hip_bfloat16*)alloc((size_t)BL_ * DM_ / 2);
    __hip_bfloat16* u_bf  = (__hip_bfloat16*)alloc((size_t)BL_ * DI_ / 2);
    __hip_bfloat16* y_bf  = (__hip_bfloat16*)alloc((size_t)BL_ * DI_ / 2);
    __hip_bfloat16* WiT   = (__hip_bfloat16*)alloc((size_t)DM_ * F_ / 2);
    __hip_bfloat16* x_bf  = (__hip_bfloat16*)alloc((size_t)BL_ * F_ / 2);
    __hip_bfloat16* inT   = (__hip_bfloat16*)alloc((size_t)NL_ * NXZ_ * DM_ / 2);
    __hip_bfloat16* outT  = (__hip_bfloat16*)alloc((size_t)NL_ * DM_ * DI_ / 2);
    __hip_bfloat16* xprT  = (__hip_bfloat16*)alloc((size_t)NL_ * 128 * DI_ / 2);

    const dim3 blk(256);
    const dim3 tblk(32, 8);

    // ---- all weight conversions up front (layer-batched via gridDim.z) ----
    cvt_bf16<<<(BL_ * F_ + 255) / 256, blk, 0, stream>>>(x, x_bf, BL_ * F_);
    transpose_f32_bf16<<<dim3(DM_ / 32, F_ / 32, 1), tblk, 0, stream>>>(
        Wi, WiT, F_, DM_, F_, 0, 0);
    transpose_f32_bf16<<<dim3(NXZ_ / 32, DM_ / 32, NL_), tblk, 0, stream>>>(
        in_w, inT, DM_, NXZ_, DM_, (size_t)DM_ * NXZ_, (size_t)NXZ_ * DM_);
    transpose_f32_bf16<<<dim3(DM_ / 32, DI_ / 32, NL_), tblk, 0, stream>>>(
        out_w, outT, DI_, DM_, DI_, (size_t)DI_ * DM_, (size_t)DM_ * DI_);
    transpose_f32_bf16<<<dim3(128 / 32, DI_ / 32, NL_), tblk, 0, stream>>>(
        xproj, xprT, DI_, DBC_, DI_, (size_t)DI_ * DBC_, (size_t)128 * DI_);

    // input projection: h = x @ Wi + bi  (BN=64, dbuf)
    gemm_mfma<64, float, true, false, false, false>
        <<<dim3(DM_ / 64, BL_ / 128), blk, 0, stream>>>(
        x_bf, WiT, h, DM_, bi, F_, DM_);

    for (int i = 0; i < NL_; ++i) {
        // ln + side-job: zero dbc for the split-K xproj below
        ln_rows<__hip_bfloat16><<<BL_, blk, 0, stream>>>(
            h, ln_g + i * DM_, ln_b + i * DM_, hn_bf, dbc, BL_ * DBC_);

        // xz: BN=128, single-buffered (32 MFMA per barrier pair) -> 768 blocks
        gemm_mfma<128, __hip_bfloat16, false, false, false, false, 1, false>
            <<<dim3(NXZ_ / 128, BL_ / 128), blk, 0, stream>>>(
            hn_bf, inT + (size_t)i * NXZ_ * DM_, xz_bf, NXZ_, nullptr, DM_, NXZ_);

        conv_silu<<<(DI_ / 256) * (L_ / LBLK) * B_, blk, 0, stream>>>(
            xz_bf, conv_w + (size_t)i * DI_ * DC_, conv_b + (size_t)i * DI_, u_bf);

        gemm_mfma<64, float, false, false, false, true, 8>
            <<<dim3(2, BL_ / 128, 8), blk, 0, stream>>>(
            u_bf, xprT + (size_t)i * 128 * DI_, dbc, DBC_, nullptr, DI_, DBC_);

        // pass A with fused dt (no gemm_dt kernel)
        scan_passA<<<(B_ * NCH_ * DI_) / 256, blk, 0, stream>>>(
            dbc, u_bf, A_log + (size_t)i * DI_ * DS_,
            dt_w + (size_t)i * DR_ * DI_, dt_b + (size_t)i * DI_,
            cs, csum, delta);
        scan_passB<<<(B_ * DS_ * DI_) / 256, blk, 0, stream>>>(
            cs, csum, A_log + (size_t)i * DI_ * DS_);
        scan_passC<<<(B_ * NCH_ * DI_) / 256, blk, 0, stream>>>(
            delta, u_bf, dbc, A_log + (size_t)i * DI_ * DS_, cs, Dvp + (size_t)i * DI_,
            xz_bf, y_bf);

        // out-proj: BN=128 single-buffered, split-K x2 -> 384 blocks
        gemm_mfma<128, float, false, false, false, false, 2, false>
            <<<dim3(DM_ / 128, BL_ / 128, 2), blk, 0, stream>>>(
            y_bf, outT + (size_t)i * DM_ * DI_, h, DM_, nullptr, DI_, DM_);
    }

    ln_rows<float><<<BL_, blk, 0, stream>>>(h, fn_g, fn_b, out, nullptr, 0);
}